// Round 2
// baseline (55028.290 us; speedup 1.0000x reference)
//
#include <hip/hip_runtime.h>
#include <cstdint>

#define T_STEPS 131072
#define FEATS 128
#define HID 64
#define LAT 16
#define GATES 256  // 4*HID

typedef float v4f __attribute__((ext_vector_type(4)));

#define LOG2E 1.44269504088896340736f

// ---------- math helpers ----------
__device__ __forceinline__ float frcp(float x) { return __builtin_amdgcn_rcpf(x); }
__device__ __forceinline__ float fexp2(float x) { return __builtin_amdgcn_exp2f(x); }

__device__ __forceinline__ float tanh_f(float x) {
  float ax = fabsf(x);
  float e = fexp2(ax * (-2.0f * LOG2E));
  float r = (1.0f - e) * frcp(1.0f + e);
  return copysignf(r, x);
}
__device__ __forceinline__ float prelu(float x, float a) { return x > 0.0f ? x : a * x; }

// =====================================================================
// Kernel A: xg[t][j] = b_ih[j]+b_hh[j] + sum_k x[t][k] * W_ih[j][k]
// Each block owns one j-half (128 outputs) with W^T staged in LDS (64KB).
// 2 blocks/CU co-resident. One wave per timestep, lane l -> outputs 2l,2l+1.
// =====================================================================
__global__ __launch_bounds__(256) void kA(const float* __restrict__ x,
                                          const float* __restrict__ W_ih,
                                          const float* __restrict__ b_ih,
                                          const float* __restrict__ b_hh,
                                          float* __restrict__ xg,
                                          int t0, int n) {
  __shared__ float wt[FEATS * 128];                 // [k][jj] transposed half
  __shared__ __align__(16) float xb[4][FEATS];      // per-wave x row
  const int tid = threadIdx.x;
  const int w = tid >> 6, l = tid & 63;
  const int half = blockIdx.x & 1;
  const int pair = blockIdx.x >> 1;                 // 0..255

  for (int idx = tid; idx < 128 * FEATS; idx += 256) {
    int jj = idx >> 7, k = idx & 127;
    wt[k * 128 + jj] = W_ih[(size_t)(half * 128 + jj) * FEATS + k];
  }
  const int j0 = half * 128 + 2 * l;
  const float b0 = b_ih[j0] + b_hh[j0];
  const float b1 = b_ih[j0 + 1] + b_hh[j0 + 1];
  __syncthreads();

  for (int s = pair * 4 + w; s < n; s += 1024) {
    const size_t t = (size_t)(t0 + s);
    *(float2*)&xb[w][2 * l] = *(const float2*)&x[t * FEATS + 2 * l];
    float a0 = b0, a0b = 0.f, a1 = b1, a1b = 0.f;
#pragma unroll
    for (int k = 0; k < FEATS; k += 4) {
      float4 xk = *(const float4*)&xb[w][k];
      float2 w0 = *(const float2*)&wt[(k + 0) * 128 + 2 * l];
      float2 w1 = *(const float2*)&wt[(k + 1) * 128 + 2 * l];
      float2 w2 = *(const float2*)&wt[(k + 2) * 128 + 2 * l];
      float2 w3 = *(const float2*)&wt[(k + 3) * 128 + 2 * l];
      a0  += xk.x * w0.x; a0b += xk.y * w1.x;
      a0  += xk.z * w2.x; a0b += xk.w * w3.x;
      a1  += xk.x * w0.y; a1b += xk.y * w1.y;
      a1  += xk.z * w2.y; a1b += xk.w * w3.y;
    }
    *(float2*)&xg[(size_t)s * GATES + j0] = make_float2(a0 + a0b, a1 + a1b);
  }
}

// =====================================================================
// Kernel B: the sequential LSTM recurrence. ONE block, 256 threads.
// thread = (gate g, element e); owns W_hh row in 64 VGPRs (v4f x16).
// h double-buffered in LDS; ONE raw barrier per step (lgkmcnt only, so the
// distance-4 xg prefetch + h2 stores stay in flight across barriers).
// h2 stream is written into out[t*128 + e] (aliased; kC re-reads then
// overwrites the same row within one wave).
// =====================================================================
#define BAR() asm volatile("s_waitcnt lgkmcnt(0)\ns_barrier" ::: "memory")

__global__ __launch_bounds__(256, 1) void kB(const float* __restrict__ xg,
                                             const float* __restrict__ W_hh,
                                             const float* __restrict__ h0,
                                             const float* __restrict__ c0,
                                             float* __restrict__ state,
                                             float* __restrict__ h2out,
                                             int t0, int nsteps, int first) {
  __shared__ __align__(16) float hbuf[2][HID];
  const int tid = threadIdx.x;
  const int w = tid >> 6;
  const int lane = tid & 63;
  const int le = lane & 15;
  const int g = lane >> 4;
  const int e = (w << 4) | le;       // element 0..63
  const int j = (g << 6) | e;        // gate row 0..255
  const bool isg2 = (g == 2);
  const float kmul2 = isg2 ? (-2.0f * LOG2E) : (-LOG2E);
  const int adr_f = (16 + le) << 2;  // bpermute byte addrs (hoisted)
  const int adr_g = (32 + le) << 2;
  const int adr_o = (48 + le) << 2;

  v4f wreg[16];
#pragma unroll
  for (int k = 0; k < 16; ++k) wreg[k] = *(const v4f*)&W_hh[(size_t)j * HID + 4 * k];

  if (tid < HID) hbuf[0][tid] = first ? h0[tid] : state[tid];
  float c_reg = (lane < 16) ? (first ? c0[e] : state[HID + e]) : 0.0f;

  float x0 = xg[(size_t)0 * GATES + j];
  float x1 = xg[(size_t)1 * GATES + j];
  float x2 = xg[(size_t)2 * GATES + j];
  float x3 = xg[(size_t)3 * GATES + j];
  __syncthreads();

#define LSTM_STEP(XV, S, CUR)                                              \
  {                                                                        \
    const v4f* hb4 = (const v4f*)hbuf[CUR];                                \
    v4f ac0 = {(XV), 0.f, 0.f, 0.f};                                       \
    v4f ac1 = {0.f, 0.f, 0.f, 0.f};                                        \
    v4f ac2 = {0.f, 0.f, 0.f, 0.f};                                        \
    v4f ac3 = {0.f, 0.f, 0.f, 0.f};                                        \
    _Pragma("unroll")                                                      \
    for (int kk = 0; kk < 16; kk += 4) {                                   \
      ac0 = __builtin_elementwise_fma(hb4[kk + 0], wreg[kk + 0], ac0);     \
      ac1 = __builtin_elementwise_fma(hb4[kk + 1], wreg[kk + 1], ac1);     \
      ac2 = __builtin_elementwise_fma(hb4[kk + 2], wreg[kk + 2], ac2);     \
      ac3 = __builtin_elementwise_fma(hb4[kk + 3], wreg[kk + 3], ac3);     \
    }                                                                      \
    v4f av = (ac0 + ac1) + (ac2 + ac3);                                    \
    float acc = (av.x + av.y) + (av.z + av.w);                             \
    float ax = fabsf(acc);                                                 \
    float e_ = fexp2(kmul2 * ax);                                          \
    float rn = frcp(1.0f + e_);                                            \
    float pos = isg2 ? (1.0f - e_) * rn : rn;                              \
    float neg = isg2 ? -pos : e_ * rn;                                     \
    float a = (acc >= 0.0f) ? pos : neg;                                   \
    int ai = __float_as_int(a);                                            \
    float fv = __int_as_float(__builtin_amdgcn_ds_bpermute(adr_f, ai));    \
    float gv = __int_as_float(__builtin_amdgcn_ds_bpermute(adr_g, ai));    \
    float ov = __int_as_float(__builtin_amdgcn_ds_bpermute(adr_o, ai));    \
    float c2 = fv * c_reg + a * gv;                                        \
    float h2v = ov * tanh_f(c2);                                           \
    c_reg = c2;                                                            \
    if (lane < 16) {                                                       \
      hbuf[(CUR) ^ 1][e] = h2v;                                            \
      h2out[(size_t)(t0 + (S)) * 128 + e] = h2v;                           \
    }                                                                      \
    BAR();                                                                 \
  }

  for (int s = 0; s < nsteps; s += 4) {
    { float nx = xg[(size_t)(s + 4) * GATES + j]; LSTM_STEP(x0, s + 0, 0); x0 = nx; }
    { float nx = xg[(size_t)(s + 5) * GATES + j]; LSTM_STEP(x1, s + 1, 1); x1 = nx; }
    { float nx = xg[(size_t)(s + 6) * GATES + j]; LSTM_STEP(x2, s + 2, 0); x2 = nx; }
    { float nx = xg[(size_t)(s + 7) * GATES + j]; LSTM_STEP(x3, s + 3, 1); x3 = nx; }
  }
  if (tid < HID) state[tid] = hbuf[0][tid];   // nsteps%4==0 -> final h in buf 0
  if (lane < 16) state[HID + e] = c_reg;
#undef LSTM_STEP
}

// =====================================================================
// Kernel C: VAE encoder/decoder, fully parallel over t. One wave per t,
// 8 waves/block, all weights transposed in LDS (~98KB), ping-pong act bufs.
// h2 arrives in out[t*128+0..63]; row is overwritten by the same wave at
// the end of the iteration.
// =====================================================================
__device__ __forceinline__ void stageT(float* dst, const float* __restrict__ src,
                                       int rows, int colsShift, int tid, int nthr) {
  const int total = rows << colsShift;
  const int cmask = (1 << colsShift) - 1;
  for (int idx = tid; idx < total; idx += nthr) {
    int jr = idx >> colsShift, k = idx & cmask;
    dst[k * rows + jr] = src[idx];
  }
}

__global__ __launch_bounds__(512) void kC(const float* __restrict__ eps,
                                          const int* __restrict__ trainp,
                                          const float* __restrict__ We1, const float* __restrict__ be1, const float* __restrict__ ae1,
                                          const float* __restrict__ We2, const float* __restrict__ be2, const float* __restrict__ ae2,
                                          const float* __restrict__ We3, const float* __restrict__ be3,
                                          const float* __restrict__ Wd1, const float* __restrict__ bd1, const float* __restrict__ ad1,
                                          const float* __restrict__ Wd2, const float* __restrict__ bd2, const float* __restrict__ ad2,
                                          const float* __restrict__ Wd3, const float* __restrict__ bd3,
                                          float* __restrict__ out) {
  __shared__ float wt1[4096], wt2[4096], wt3[2048], wtd1[1024], wtd2[4096], wtd3[8192];
  __shared__ float bb[416];
  __shared__ __align__(16) float abuf[8][2][HID];
  const int tid = threadIdx.x;

  stageT(wt1, We1, 64, 6, tid, 512);
  stageT(wt2, We2, 64, 6, tid, 512);
  stageT(wt3, We3, 32, 6, tid, 512);
  stageT(wtd1, Wd1, 64, 4, tid, 512);
  stageT(wtd2, Wd2, 64, 6, tid, 512);
  stageT(wtd3, Wd3, 128, 6, tid, 512);
  for (int i = tid; i < 416; i += 512) {
    float v;
    if (i < 64)       v = be1[i];
    else if (i < 128) v = be2[i - 64];
    else if (i < 160) v = be3[i - 128];
    else if (i < 224) v = bd1[i - 160];
    else if (i < 288) v = bd2[i - 224];
    else              v = bd3[i - 288];
    bb[i] = v;
  }
  const float a1 = *ae1, a2 = *ae2, ad1v = *ad1, ad2v = *ad2;
  const int train = *trainp;
  __syncthreads();

  const int w = tid >> 6, l = tid & 63, le = l & 15;
  float* bufA = abuf[w][0];
  float* bufB = abuf[w][1];

  for (int it = 0; it < 64; ++it) {
    const size_t t = ((size_t)blockIdx.x << 9) + (size_t)(it << 3) + (size_t)w;
    bufA[l] = out[t * 128 + l];  // h2 row (written by kB)
    // e1 = prelu(We1 . h2 + be1): bufA -> bufB
    {
      float accA = bb[l], accB = 0.f;
#pragma unroll
      for (int k = 0; k < 64; k += 4) {
        float4 v = *(const float4*)&bufA[k];
        accA += v.x * wt1[(k + 0) * 64 + l];
        accB += v.y * wt1[(k + 1) * 64 + l];
        accA += v.z * wt1[(k + 2) * 64 + l];
        accB += v.w * wt1[(k + 3) * 64 + l];
      }
      bufB[l] = prelu(accA + accB, a1);
    }
    // e2: bufB -> bufA
    {
      float accA = bb[64 + l], accB = 0.f;
#pragma unroll
      for (int k = 0; k < 64; k += 4) {
        float4 v = *(const float4*)&bufB[k];
        accA += v.x * wt2[(k + 0) * 64 + l];
        accB += v.y * wt2[(k + 1) * 64 + l];
        accA += v.z * wt2[(k + 2) * 64 + l];
        accB += v.w * wt2[(k + 3) * 64 + l];
      }
      bufA[l] = prelu(accA + accB, a2);
    }
    // ml = We3 . e2 + be3 (32 outputs in lanes 0..31)
    float m;
    {
      const int jj = l & 31;
      float accA = bb[128 + jj], accB = 0.f;
#pragma unroll
      for (int k = 0; k < 64; k += 4) {
        float4 v = *(const float4*)&bufA[k];
        accA += v.x * wt3[(k + 0) * 32 + jj];
        accB += v.y * wt3[(k + 1) * 32 + jj];
        accA += v.z * wt3[(k + 2) * 32 + jj];
        accB += v.w * wt3[(k + 3) * 32 + jj];
      }
      m = accA + accB;
    }
    if (l < 16)      out[(size_t)T_STEPS * 128 + t * LAT + l] = m;          // mu
    else if (l < 32) out[(size_t)T_STEPS * 144 + t * LAT + (l - 16)] = m;   // lv
    float muv = __shfl(m, le);
    float lvv = __shfl(m, 16 + le);
    float ev = eps[t * LAT + le];
    float z = train ? (muv + ev * fexp2(0.5f * LOG2E * lvv)) : muv;
    if (l < 16) bufB[l] = z;
    // d1 = prelu(Wd1 . z + bd1): bufB(16) -> bufA
    {
      float accA = bb[160 + l], accB = 0.f;
#pragma unroll
      for (int k = 0; k < 16; k += 4) {
        float4 v = *(const float4*)&bufB[k];
        accA += v.x * wtd1[(k + 0) * 64 + l];
        accB += v.y * wtd1[(k + 1) * 64 + l];
        accA += v.z * wtd1[(k + 2) * 64 + l];
        accB += v.w * wtd1[(k + 3) * 64 + l];
      }
      bufA[l] = prelu(accA + accB, ad1v);
    }
    // d2: bufA -> bufB
    {
      float accA = bb[224 + l], accB = 0.f;
#pragma unroll
      for (int k = 0; k < 64; k += 4) {
        float4 v = *(const float4*)&bufA[k];
        accA += v.x * wtd2[(k + 0) * 64 + l];
        accB += v.y * wtd2[(k + 1) * 64 + l];
        accA += v.z * wtd2[(k + 2) * 64 + l];
        accB += v.w * wtd2[(k + 3) * 64 + l];
      }
      bufB[l] = prelu(accA + accB, ad2v);
    }
    // out = 4*tanh(Wd3 . d2 + bd3): lane l -> outputs 2l, 2l+1
    {
      float acc0 = bb[288 + 2 * l], acc0b = 0.f;
      float acc1 = bb[288 + 2 * l + 1], acc1b = 0.f;
#pragma unroll
      for (int k = 0; k < 64; k += 2) {
        float2 v = *(const float2*)&bufB[k];
        float2 w0 = *(const float2*)&wtd3[(k + 0) * 128 + 2 * l];
        float2 w1 = *(const float2*)&wtd3[(k + 1) * 128 + 2 * l];
        acc0  += v.x * w0.x; acc0b += v.y * w1.x;
        acc1  += v.x * w0.y; acc1b += v.y * w1.y;
      }
      float o0 = 4.0f * tanh_f(acc0 + acc0b);
      float o1 = 4.0f * tanh_f(acc1 + acc1b);
      *(float2*)&out[t * 128 + 2 * l] = make_float2(o0, o1);
    }
  }
}

// =====================================================================
extern "C" void kernel_launch(void* const* d_in, const int* in_sizes, int n_in,
                              void* d_out, int out_size, void* d_ws, size_t ws_size,
                              hipStream_t stream) {
  (void)in_sizes; (void)n_in; (void)out_size;
  const float* x    = (const float*)d_in[0];
  const float* eps  = (const float*)d_in[1];
  const float* h0   = (const float*)d_in[2];
  const float* c0   = (const float*)d_in[3];
  const int*   tr   = (const int*)d_in[4];
  const float* W_ih = (const float*)d_in[5];
  const float* W_hh = (const float*)d_in[6];
  const float* b_ih = (const float*)d_in[7];
  const float* b_hh = (const float*)d_in[8];
  const float* We1  = (const float*)d_in[9];
  const float* be1  = (const float*)d_in[10];
  const float* ae1  = (const float*)d_in[11];
  const float* We2  = (const float*)d_in[12];
  const float* be2  = (const float*)d_in[13];
  const float* ae2  = (const float*)d_in[14];
  const float* We3  = (const float*)d_in[15];
  const float* be3  = (const float*)d_in[16];
  const float* Wd1  = (const float*)d_in[17];
  const float* bd1  = (const float*)d_in[18];
  const float* ad1  = (const float*)d_in[19];
  const float* Wd2  = (const float*)d_in[20];
  const float* bd2  = (const float*)d_in[21];
  const float* ad2  = (const float*)d_in[22];
  const float* Wd3  = (const float*)d_in[23];
  const float* bd3  = (const float*)d_in[24];
  float* out = (float*)d_out;

  // ws layout: [state: 1024B][xg: (ch+8)*1024B]
  char* ws = (char*)d_ws;
  float* state = (float*)ws;
  float* xg    = (float*)(ws + 1024);

  long fit = (ws_size > 2048) ? (long)((ws_size - 1024) / (GATES * sizeof(float))) - 8 : 0;
  long ch = (fit < (long)T_STEPS) ? fit : (long)T_STEPS;
  ch &= ~3L;
  if (ch < 1024) ch = 1024;  // bounds graph at <=129 chunk pairs

  for (long t0 = 0; t0 < T_STEPS; t0 += ch) {
    int n = (int)(((long)T_STEPS - t0 < ch) ? ((long)T_STEPS - t0) : ch);
    hipLaunchKernelGGL(kA, dim3(512), dim3(256), 0, stream,
                       x, W_ih, b_ih, b_hh, xg, (int)t0, n);
    hipLaunchKernelGGL(kB, dim3(1), dim3(256), 0, stream,
                       xg, W_hh, h0, c0, state, out, (int)t0, n, (t0 == 0) ? 1 : 0);
  }
  hipLaunchKernelGGL(kC, dim3(256), dim3(512), 0, stream,
                     eps, tr, We1, be1, ae1, We2, be2, ae2, We3, be3,
                     Wd1, bd1, ad1, Wd2, bd2, ad2, Wd3, bd3, out);
}